// Round 3
// baseline (192.391 us; speedup 1.0000x reference)
//
#include <hip/hip_runtime.h>

#define DIM 128
#define EPS 1e-5f

typedef short           bf16x8 __attribute__((ext_vector_type(8)));
typedef unsigned short  u16x4  __attribute__((ext_vector_type(4)));
typedef float           f32x4  __attribute__((ext_vector_type(4)));

__device__ __forceinline__ unsigned short f2b(float f) {
    unsigned int u = __builtin_bit_cast(unsigned int, f);
    unsigned int r = (u + 0x7FFFu + ((u >> 16) & 1u)) >> 16;   // RNE
    return (unsigned short)r;
}
// pack 8 consecutive f32 -> bf16x8 fragment
__device__ __forceinline__ bf16x8 ldw8(const float* __restrict__ p) {
    f32x4 a = *reinterpret_cast<const f32x4*>(p);
    f32x4 b = *reinterpret_cast<const f32x4*>(p + 4);
    bf16x8 r;
    #pragma unroll
    for (int j = 0; j < 4; ++j) {
        r[j]     = (short)f2b(a[j]);
        r[j + 4] = (short)f2b(b[j]);
    }
    return r;
}

// ---------------------------------------------------------------------------
// K1: per-graph segment mean pool + add vn_h  ->  x_ws (bf16 [B][128])
// one block per graph; batch is sorted so the segment is contiguous.
// ---------------------------------------------------------------------------
__global__ __launch_bounds__(256) void k_pool(
    const float* __restrict__ h, const int* __restrict__ batch,
    const float* __restrict__ vn, unsigned short* __restrict__ x_ws,
    int n_nodes)
{
    const int b   = blockIdx.x;
    const int tid = threadIdx.x;
    __shared__ int sb[2];
    if (tid < 2) {
        const int target = b + tid;
        int lo = 0, hi = n_nodes;
        while (lo < hi) {
            int mid = (lo + hi) >> 1;
            if (batch[mid] < target) lo = mid + 1; else hi = mid;
        }
        sb[tid] = lo;
    }
    __syncthreads();
    const int s = sb[0], e = sb[1];

    const int oct = tid & 31;   // float4 slot: features oct*4 .. oct*4+3
    const int rg  = tid >> 5;   // row group 0..7

    f32x4 acc = (f32x4){0.f, 0.f, 0.f, 0.f};
    for (int n = s + rg; n < e; n += 8)
        acc += *reinterpret_cast<const f32x4*>(h + (size_t)n * DIM + oct * 4);

    __shared__ f32x4 red[256];
    red[tid] = acc;
    __syncthreads();

    if (tid < 32) {
        f32x4 a = red[tid];
        #pragma unroll
        for (int i = 1; i < 8; ++i) a += red[tid + 32 * i];

        const int cnt = e - s;
        const float inv = 1.0f / (float)(cnt > 1 ? cnt : 1);
        f32x4 vv = *reinterpret_cast<const f32x4*>(vn + (size_t)b * DIM + tid * 4);
        u16x4 ov;
        #pragma unroll
        for (int j = 0; j < 4; ++j) ov[j] = f2b(fmaf(a[j], inv, vv[j]));
        *reinterpret_cast<u16x4*>(x_ws + (size_t)b * DIM + tid * 4) = ov;
    }
}

// ---------------------------------------------------------------------------
// K2: vn MLP  x -> Linear(W1,b1) -> LayerNorm -> ReLU -> Linear(W2,b2)
// MFMA 16x16x32 bf16. One wave per 16 graphs; 4 waves/block.
// A/B share the same (kgrp,kk,i)->k memory mapping, so the dot product is
// correct for any HW k-permutation. C/D (m89): col n=lane&15, row m=(lane>>4)*4+reg.
// Output written directly to vn_out as f32.
// ---------------------------------------------------------------------------
__global__ __launch_bounds__(256) void k_mlp(
    const unsigned short* __restrict__ x_ws,
    const float* __restrict__ W1, const float* __restrict__ b1,
    const float* __restrict__ lng, const float* __restrict__ lnb,
    const float* __restrict__ W2, const float* __restrict__ b2v,
    float* __restrict__ vn_out)
{
    __shared__ unsigned short zt[4][16][136];   // padded stride

    const int wave  = threadIdx.x >> 6;
    const int lane  = threadIdx.x & 63;
    const int gtile = blockIdx.x * 4 + wave;    // 16-graph tile index
    const int row16 = lane & 15;
    const int kgrp  = lane >> 4;                // 0..3

    // ---- layer 1: Y = X @ W1^T ----
    bf16x8 afrag[4];
    {
        const unsigned short* xp =
            x_ws + (size_t)(gtile * 16 + row16) * DIM + kgrp * 8;
        #pragma unroll
        for (int kk = 0; kk < 4; ++kk)
            afrag[kk] = *reinterpret_cast<const bf16x8*>(xp + kk * 32);
    }
    f32x4 acc[8];
    #pragma unroll
    for (int t = 0; t < 8; ++t) acc[t] = (f32x4){0.f, 0.f, 0.f, 0.f};
    #pragma unroll
    for (int t = 0; t < 8; ++t) {
        const float* wp = W1 + (size_t)(t * 16 + row16) * DIM + kgrp * 8;
        #pragma unroll
        for (int kk = 0; kk < 4; ++kk) {
            bf16x8 bfrag = ldw8(wp + kk * 32);
            acc[t] = __builtin_amdgcn_mfma_f32_16x16x32_bf16(afrag[kk], bfrag, acc[t], 0, 0, 0);
        }
    }

    // per-lane feature params (feature f = t*16 + row16)
    float b1f[8], gf[8], bf_[8], b2f8[8];
    #pragma unroll
    for (int t = 0; t < 8; ++t) {
        const int f = t * 16 + row16;
        b1f[t]  = b1[f];
        gf[t]   = lng[f];
        bf_[t]  = lnb[f];
        b2f8[t] = b2v[f];
    }
    #pragma unroll
    for (int t = 0; t < 8; ++t)
        #pragma unroll
        for (int r = 0; r < 4; ++r) acc[t][r] += b1f[t];

    // ---- LayerNorm + ReLU, write z (bf16) to LDS transposed tile ----
    #pragma unroll
    for (int r = 0; r < 4; ++r) {
        float s = 0.f, ss = 0.f;
        #pragma unroll
        for (int t = 0; t < 8; ++t) { s += acc[t][r]; ss += acc[t][r] * acc[t][r]; }
        #pragma unroll
        for (int m = 1; m <= 8; m <<= 1) {      // reduce across the 16-lane group
            s  += __shfl_xor(s,  m);
            ss += __shfl_xor(ss, m);
        }
        const float mu  = s * (1.0f / 128.0f);
        const float var = ss * (1.0f / 128.0f) - mu * mu;
        const float rs  = rsqrtf(var + EPS);
        const int   gm  = kgrp * 4 + r;         // graph row within tile
        #pragma unroll
        for (int t = 0; t < 8; ++t) {
            float z = (acc[t][r] - mu) * rs * gf[t] + bf_[t];
            z = fmaxf(z, 0.f);
            zt[wave][gm][t * 16 + row16] = f2b(z);
        }
    }
    __syncthreads();

    // ---- layer 2: O = Z @ W2^T ----
    bf16x8 afrag2[4];
    #pragma unroll
    for (int kk = 0; kk < 4; ++kk)
        afrag2[kk] = *reinterpret_cast<const bf16x8*>(&zt[wave][row16][kk * 32 + kgrp * 8]);

    f32x4 acc2[8];
    #pragma unroll
    for (int t = 0; t < 8; ++t) acc2[t] = (f32x4){0.f, 0.f, 0.f, 0.f};
    #pragma unroll
    for (int t = 0; t < 8; ++t) {
        const float* wp = W2 + (size_t)(t * 16 + row16) * DIM + kgrp * 8;
        #pragma unroll
        for (int kk = 0; kk < 4; ++kk) {
            bf16x8 bfrag = ldw8(wp + kk * 32);
            acc2[t] = __builtin_amdgcn_mfma_f32_16x16x32_bf16(afrag2[kk], bfrag, acc2[t], 0, 0, 0);
        }
    }

    // ---- direct f32 store: O[graph kgrp*4+r][feature t*16+row16] ----
    #pragma unroll
    for (int r = 0; r < 4; ++r) {
        float* op = vn_out + (size_t)(gtile * 16 + kgrp * 4 + r) * DIM + row16;
        #pragma unroll
        for (int t = 0; t < 8; ++t)
            op[t * 16] = acc2[t][r] + b2f8[t];
    }
}

// ---------------------------------------------------------------------------
// K3: h_out = h + vn_out[batch]   (vn_out is 4 MB f32, L2-resident)
// ---------------------------------------------------------------------------
__global__ __launch_bounds__(256) void k_add(
    const float* __restrict__ h, const int* __restrict__ batch,
    const float* __restrict__ vn_out, float* __restrict__ h_out,
    int n_nodes)
{
    const long total = (long)n_nodes * 16;     // 16 8-feature units per row
    for (long u = (long)blockIdx.x * blockDim.x + threadIdx.x; u < total;
         u += (long)gridDim.x * blockDim.x) {
        const int n = (int)(u >> 4);
        const int c = ((int)u & 15) * 8;
        const float* hp = h + (size_t)n * DIM + c;
        f32x4 h0 = *reinterpret_cast<const f32x4*>(hp);
        f32x4 h1 = *reinterpret_cast<const f32x4*>(hp + 4);
        const int b = batch[n];
        const float* vp = vn_out + (size_t)b * DIM + c;
        f32x4 v0 = *reinterpret_cast<const f32x4*>(vp);
        f32x4 v1 = *reinterpret_cast<const f32x4*>(vp + 4);
        float* op = h_out + (size_t)n * DIM + c;
        *reinterpret_cast<f32x4*>(op)     = h0 + v0;
        *reinterpret_cast<f32x4*>(op + 4) = h1 + v1;
    }
}

// ---------------------------------------------------------------------------
extern "C" void kernel_launch(void* const* d_in, const int* in_sizes, int n_in,
                              void* d_out, int out_size, void* d_ws, size_t ws_size,
                              hipStream_t stream)
{
    const float* h    = (const float*)d_in[0];
    const int*   bat  = (const int*)d_in[1];
    const float* vn   = (const float*)d_in[2];
    const float* W1   = (const float*)d_in[3];
    const float* b1   = (const float*)d_in[4];
    const float* lng  = (const float*)d_in[5];
    const float* lnb  = (const float*)d_in[6];
    const float* W2   = (const float*)d_in[7];
    const float* b2v  = (const float*)d_in[8];

    const int n_nodes = in_sizes[0] / DIM;   // 500000
    const int nb      = in_sizes[2] / DIM;   // 8192

    float* out    = (float*)d_out;           // f32 output buffer
    float* h_out  = out;
    float* vn_out = out + (size_t)n_nodes * DIM;
    unsigned short* x_ws = (unsigned short*)d_ws;   // nb*128 bf16 = 2 MB

    k_pool<<<nb, 256, 0, stream>>>(h, bat, vn, x_ws, n_nodes);
    k_mlp <<<nb / 64, 256, 0, stream>>>(x_ws, W1, b1, lng, lnb, W2, b2v, vn_out);
    k_add <<<2048, 256, 0, stream>>>(h, bat, vn_out, h_out, n_nodes);
}

// Round 4
// 154.881 us; speedup vs baseline: 1.2422x; 1.2422x over previous
//
#include <hip/hip_runtime.h>

#define DIM 128
#define EPS 1e-5f

typedef short           bf16x8 __attribute__((ext_vector_type(8)));
typedef unsigned short  u16x4  __attribute__((ext_vector_type(4)));
typedef float           f32x4  __attribute__((ext_vector_type(4)));

__device__ __forceinline__ unsigned short f2b(float f) {
    unsigned int u = __builtin_bit_cast(unsigned int, f);
    unsigned int r = (u + 0x7FFFu + ((u >> 16) & 1u)) >> 16;   // RNE
    return (unsigned short)r;
}
// pack 8 consecutive f32 -> bf16x8 fragment
__device__ __forceinline__ bf16x8 ldw8(const float* __restrict__ p) {
    f32x4 a = *reinterpret_cast<const f32x4*>(p);
    f32x4 b = *reinterpret_cast<const f32x4*>(p + 4);
    bf16x8 r;
    #pragma unroll
    for (int j = 0; j < 4; ++j) {
        r[j]     = (short)f2b(a[j]);
        r[j + 4] = (short)f2b(b[j]);
    }
    return r;
}

// ---------------------------------------------------------------------------
// K1 (fused): pool 16 graphs per block + vn_h add + 2-layer MFMA MLP.
// 256 threads = 16 graphs x 16 lanes. Each graph's 16 lanes walk its
// contiguous segment (batch sorted), accumulating 2 f32x4 quads/row in
// registers -> no LDS reduce, no atomics. Wave 0 then runs the MLP for the
// block's 16-graph tile and writes vn_out (f32).
// ---------------------------------------------------------------------------
__global__ __launch_bounds__(256) void k_pool_mlp(
    const float* __restrict__ h, const int* __restrict__ batch,
    const float* __restrict__ vn,
    const float* __restrict__ W1, const float* __restrict__ b1,
    const float* __restrict__ lng, const float* __restrict__ lnb,
    const float* __restrict__ W2, const float* __restrict__ b2v,
    float* __restrict__ vn_out, int n_nodes)
{
    __shared__ int sb[17];
    __shared__ unsigned short xtile[16][136];   // padded stride (bank spread)

    const int tid = threadIdx.x;
    const int G0  = blockIdx.x * 16;

    if (tid < 17) {
        const int target = G0 + tid;
        int lo = 0, hi = n_nodes;
        while (lo < hi) {
            int mid = (lo + hi) >> 1;
            if (batch[mid] < target) lo = mid + 1; else hi = mid;
        }
        sb[tid] = lo;
    }
    __syncthreads();

    // ---- register-accumulated segment pool ----
    const int gi = tid >> 4;    // graph within tile (0..15)
    const int j  = tid & 15;    // quad slot (features j*4..j*4+3 and +64)
    const int s = sb[gi], e = sb[gi + 1];

    f32x4 a0 = (f32x4){0.f, 0.f, 0.f, 0.f};
    f32x4 a1 = (f32x4){0.f, 0.f, 0.f, 0.f};
    for (int n = s; n < e; ++n) {
        const float* p = h + (size_t)n * DIM + j * 4;
        a0 += *reinterpret_cast<const f32x4*>(p);
        a1 += *reinterpret_cast<const f32x4*>(p + 64);
    }

    const int cnt = e - s;
    const float inv = 1.0f / (float)(cnt > 1 ? cnt : 1);
    const float* vp = vn + (size_t)(G0 + gi) * DIM + j * 4;
    f32x4 v0 = *reinterpret_cast<const f32x4*>(vp);
    f32x4 v1 = *reinterpret_cast<const f32x4*>(vp + 64);
    u16x4 x0, x1;
    #pragma unroll
    for (int q = 0; q < 4; ++q) {
        x0[q] = f2b(fmaf(a0[q], inv, v0[q]));
        x1[q] = f2b(fmaf(a1[q], inv, v1[q]));
    }
    *reinterpret_cast<u16x4*>(&xtile[gi][j * 4])      = x0;
    *reinterpret_cast<u16x4*>(&xtile[gi][j * 4 + 64]) = x1;
    __syncthreads();

    // ---- wave 0: MLP for the 16-graph tile ----
    // A/B share the same (kgrp,kk,i)->k mapping -> k-permutation safe.
    // C/D (m89-verified): col n = lane&15, row m = (lane>>4)*4 + reg.
    if (tid < 64) {
        const int lane  = tid;
        const int row16 = lane & 15;
        const int kgrp  = lane >> 4;

        bf16x8 afrag[4];
        #pragma unroll
        for (int kk = 0; kk < 4; ++kk)
            afrag[kk] = *reinterpret_cast<const bf16x8*>(&xtile[row16][kgrp * 8 + kk * 32]);

        f32x4 acc[8];
        #pragma unroll
        for (int t = 0; t < 8; ++t) acc[t] = (f32x4){0.f, 0.f, 0.f, 0.f};
        #pragma unroll
        for (int t = 0; t < 8; ++t) {
            const float* wp = W1 + (size_t)(t * 16 + row16) * DIM + kgrp * 8;
            #pragma unroll
            for (int kk = 0; kk < 4; ++kk) {
                bf16x8 bfrag = ldw8(wp + kk * 32);
                acc[t] = __builtin_amdgcn_mfma_f32_16x16x32_bf16(afrag[kk], bfrag, acc[t], 0, 0, 0);
            }
        }

        float b1f[8], gf[8], bf_[8], b2f8[8];
        #pragma unroll
        for (int t = 0; t < 8; ++t) {
            const int f = t * 16 + row16;
            b1f[t]  = b1[f];
            gf[t]   = lng[f];
            bf_[t]  = lnb[f];
            b2f8[t] = b2v[f];
        }
        #pragma unroll
        for (int t = 0; t < 8; ++t)
            #pragma unroll
            for (int r = 0; r < 4; ++r) acc[t][r] += b1f[t];

        // LayerNorm + ReLU -> z (bf16) back into xtile (afrag already in regs)
        #pragma unroll
        for (int r = 0; r < 4; ++r) {
            float sm = 0.f, ss = 0.f;
            #pragma unroll
            for (int t = 0; t < 8; ++t) { sm += acc[t][r]; ss += acc[t][r] * acc[t][r]; }
            #pragma unroll
            for (int m = 1; m <= 8; m <<= 1) {
                sm += __shfl_xor(sm, m);
                ss += __shfl_xor(ss, m);
            }
            const float mu  = sm * (1.0f / 128.0f);
            const float var = ss * (1.0f / 128.0f) - mu * mu;
            const float rs  = rsqrtf(var + EPS);
            const int   gm  = kgrp * 4 + r;
            #pragma unroll
            for (int t = 0; t < 8; ++t) {
                float z = (acc[t][r] - mu) * rs * gf[t] + bf_[t];
                z = fmaxf(z, 0.f);
                xtile[gm][t * 16 + row16] = f2b(z);
            }
        }
        // wave-internal LDS ordering: reads below see this wave's writes

        bf16x8 afrag2[4];
        #pragma unroll
        for (int kk = 0; kk < 4; ++kk)
            afrag2[kk] = *reinterpret_cast<const bf16x8*>(&xtile[row16][kgrp * 8 + kk * 32]);

        f32x4 acc2[8];
        #pragma unroll
        for (int t = 0; t < 8; ++t) acc2[t] = (f32x4){0.f, 0.f, 0.f, 0.f};
        #pragma unroll
        for (int t = 0; t < 8; ++t) {
            const float* wp = W2 + (size_t)(t * 16 + row16) * DIM + kgrp * 8;
            #pragma unroll
            for (int kk = 0; kk < 4; ++kk) {
                bf16x8 bfrag = ldw8(wp + kk * 32);
                acc2[t] = __builtin_amdgcn_mfma_f32_16x16x32_bf16(afrag2[kk], bfrag, acc2[t], 0, 0, 0);
            }
        }

        #pragma unroll
        for (int r = 0; r < 4; ++r) {
            float* op = vn_out + (size_t)(G0 + kgrp * 4 + r) * DIM + row16;
            #pragma unroll
            for (int t = 0; t < 8; ++t)
                op[t * 16] = acc2[t][r] + b2f8[t];
        }
    }
}

// ---------------------------------------------------------------------------
// K2: h_out = h + vn_out[batch]
// h should be L3-resident from K1's streaming read; NT stores keep the
// h_out write stream from evicting it.
// ---------------------------------------------------------------------------
__global__ __launch_bounds__(256) void k_add(
    const float* __restrict__ h, const int* __restrict__ batch,
    const float* __restrict__ vn_out, float* __restrict__ h_out,
    int n_nodes)
{
    const long total = (long)n_nodes * 16;     // 16 8-float units per row
    for (long u = (long)blockIdx.x * blockDim.x + threadIdx.x; u < total;
         u += (long)gridDim.x * blockDim.x) {
        const int n = (int)(u >> 4);
        const int c = ((int)u & 15) * 8;
        const float* hp = h + (size_t)n * DIM + c;
        f32x4 h0 = *reinterpret_cast<const f32x4*>(hp);
        f32x4 h1 = *reinterpret_cast<const f32x4*>(hp + 4);
        const int b = batch[n];
        const float* vp = vn_out + (size_t)b * DIM + c;
        f32x4 v0 = *reinterpret_cast<const f32x4*>(vp);
        f32x4 v1 = *reinterpret_cast<const f32x4*>(vp + 4);
        float* op = h_out + (size_t)n * DIM + c;
        __builtin_nontemporal_store(h0 + v0, reinterpret_cast<f32x4*>(op));
        __builtin_nontemporal_store(h1 + v1, reinterpret_cast<f32x4*>(op + 4));
    }
}

// ---------------------------------------------------------------------------
extern "C" void kernel_launch(void* const* d_in, const int* in_sizes, int n_in,
                              void* d_out, int out_size, void* d_ws, size_t ws_size,
                              hipStream_t stream)
{
    const float* h    = (const float*)d_in[0];
    const int*   bat  = (const int*)d_in[1];
    const float* vn   = (const float*)d_in[2];
    const float* W1   = (const float*)d_in[3];
    const float* b1   = (const float*)d_in[4];
    const float* lng  = (const float*)d_in[5];
    const float* lnb  = (const float*)d_in[6];
    const float* W2   = (const float*)d_in[7];
    const float* b2v  = (const float*)d_in[8];

    const int n_nodes = in_sizes[0] / DIM;   // 500000
    const int nb      = in_sizes[2] / DIM;   // 8192

    float* out    = (float*)d_out;           // f32 output buffer
    float* h_out  = out;
    float* vn_out = out + (size_t)n_nodes * DIM;

    k_pool_mlp<<<nb / 16, 256, 0, stream>>>(h, bat, vn, W1, b1, lng, lnb,
                                            W2, b2v, vn_out, n_nodes);
    k_add<<<2048, 256, 0, stream>>>(h, bat, vn_out, h_out, n_nodes);
}

// Round 5
// 149.680 us; speedup vs baseline: 1.2853x; 1.0347x over previous
//
#include <hip/hip_runtime.h>

#define DIM 128
#define EPS 1e-5f

typedef short           bf16x8 __attribute__((ext_vector_type(8)));
typedef unsigned short  u16x8  __attribute__((ext_vector_type(8)));
typedef float           f32x4  __attribute__((ext_vector_type(4)));

__device__ __forceinline__ unsigned short f2b(float f) {
    unsigned int u = __builtin_bit_cast(unsigned int, f);
    unsigned int r = (u + 0x7FFFu + ((u >> 16) & 1u)) >> 16;   // RNE
    return (unsigned short)r;
}
// pack 8 consecutive f32 -> bf16x8 fragment
__device__ __forceinline__ bf16x8 ldw8(const float* __restrict__ p) {
    f32x4 a = *reinterpret_cast<const f32x4*>(p);
    f32x4 b = *reinterpret_cast<const f32x4*>(p + 4);
    bf16x8 r;
    #pragma unroll
    for (int j = 0; j < 4; ++j) {
        r[j]     = (short)f2b(a[j]);
        r[j + 4] = (short)f2b(b[j]);
    }
    return r;
}

// ---------------------------------------------------------------------------
// Fully fused: one block = 16 graphs (one MFMA tile).
// Phase 1: 16 lanes/graph walk the contiguous segment, pool in registers.
// Phase 2: wave 0 runs Linear->LN->ReLU->Linear via MFMA, result -> LDS vtile
//          (and nothing else: global vn_out store is done coalesced later).
// Phase 3: all 256 threads re-walk the segment rows (L2/L3-warm: fetched by
//          this same block moments ago) and NT-store h_out = h + vtile[g].
// HBM ideal: read h once (256 MB), write h_out+vn_out (260 MB).
// ---------------------------------------------------------------------------
__global__ __launch_bounds__(256) void k_fused(
    const float* __restrict__ h, const int* __restrict__ batch,
    const float* __restrict__ vn,
    const float* __restrict__ W1, const float* __restrict__ b1,
    const float* __restrict__ lng, const float* __restrict__ lnb,
    const float* __restrict__ W2, const float* __restrict__ b2v,
    float* __restrict__ vn_out, float* __restrict__ h_out, int n_nodes)
{
    __shared__ int sb[17];
    __shared__ unsigned short xtile[16][136];   // bf16 MLP input tile (padded)
    __shared__ float vtile[16][132];            // f32 MLP output tile (padded)

    const int tid = threadIdx.x;
    const int G0  = blockIdx.x * 16;

    if (tid < 17) {
        const int target = G0 + tid;
        int lo = 0, hi = n_nodes;
        while (lo < hi) {
            int mid = (lo + hi) >> 1;
            if (batch[mid] < target) lo = mid + 1; else hi = mid;
        }
        sb[tid] = lo;
    }
    __syncthreads();

    const int gi = tid >> 4;    // graph within tile (0..15)
    const int j  = tid & 15;    // 8-feature slot: features j*8 .. j*8+7
    const int s = sb[gi], e = sb[gi + 1];

    // ---- phase 1: register-accumulated segment pool ----
    f32x4 a0 = (f32x4){0.f, 0.f, 0.f, 0.f};
    f32x4 a1 = (f32x4){0.f, 0.f, 0.f, 0.f};
    for (int n = s; n < e; ++n) {
        const float* p = h + (size_t)n * DIM + j * 8;
        a0 += *reinterpret_cast<const f32x4*>(p);
        a1 += *reinterpret_cast<const f32x4*>(p + 4);
    }
    const int cnt = e - s;
    const float inv = 1.0f / (float)(cnt > 1 ? cnt : 1);
    const float* vp = vn + (size_t)(G0 + gi) * DIM + j * 8;
    f32x4 v0 = *reinterpret_cast<const f32x4*>(vp);
    f32x4 v1 = *reinterpret_cast<const f32x4*>(vp + 4);
    u16x8 xv;
    #pragma unroll
    for (int q = 0; q < 4; ++q) {
        xv[q]     = f2b(fmaf(a0[q], inv, v0[q]));
        xv[q + 4] = f2b(fmaf(a1[q], inv, v1[q]));
    }
    *reinterpret_cast<u16x8*>(&xtile[gi][j * 8]) = xv;
    __syncthreads();

    // ---- phase 2: wave 0 runs the 2-layer MFMA MLP ----
    // A/B share the same (kgrp,kk,i)->k mapping -> k-permutation safe.
    // C/D (m89-verified): col n = lane&15, row m = (lane>>4)*4 + reg.
    if (tid < 64) {
        const int lane  = tid;
        const int row16 = lane & 15;
        const int kgrp  = lane >> 4;

        bf16x8 afrag[4];
        #pragma unroll
        for (int kk = 0; kk < 4; ++kk)
            afrag[kk] = *reinterpret_cast<const bf16x8*>(&xtile[row16][kgrp * 8 + kk * 32]);

        f32x4 acc[8];
        #pragma unroll
        for (int t = 0; t < 8; ++t) acc[t] = (f32x4){0.f, 0.f, 0.f, 0.f};
        #pragma unroll
        for (int t = 0; t < 8; ++t) {
            const float* wp = W1 + (size_t)(t * 16 + row16) * DIM + kgrp * 8;
            #pragma unroll
            for (int kk = 0; kk < 4; ++kk) {
                bf16x8 bfrag = ldw8(wp + kk * 32);
                acc[t] = __builtin_amdgcn_mfma_f32_16x16x32_bf16(afrag[kk], bfrag, acc[t], 0, 0, 0);
            }
        }

        float b1f[8], gf[8], bf_[8], b2f8[8];
        #pragma unroll
        for (int t = 0; t < 8; ++t) {
            const int f = t * 16 + row16;
            b1f[t]  = b1[f];
            gf[t]   = lng[f];
            bf_[t]  = lnb[f];
            b2f8[t] = b2v[f];
        }
        #pragma unroll
        for (int t = 0; t < 8; ++t)
            #pragma unroll
            for (int r = 0; r < 4; ++r) acc[t][r] += b1f[t];

        // LayerNorm + ReLU -> z (bf16) back into xtile
        #pragma unroll
        for (int r = 0; r < 4; ++r) {
            float sm = 0.f, ss = 0.f;
            #pragma unroll
            for (int t = 0; t < 8; ++t) { sm += acc[t][r]; ss += acc[t][r] * acc[t][r]; }
            #pragma unroll
            for (int m = 1; m <= 8; m <<= 1) {
                sm += __shfl_xor(sm, m);
                ss += __shfl_xor(ss, m);
            }
            const float mu  = sm * (1.0f / 128.0f);
            const float var = ss * (1.0f / 128.0f) - mu * mu;
            const float rs  = rsqrtf(var + EPS);
            const int   gm  = kgrp * 4 + r;
            #pragma unroll
            for (int t = 0; t < 8; ++t) {
                float z = (acc[t][r] - mu) * rs * gf[t] + bf_[t];
                z = fmaxf(z, 0.f);
                xtile[gm][t * 16 + row16] = f2b(z);
            }
        }
        // wave-internal LDS ordering: reads below see this wave's writes

        bf16x8 afrag2[4];
        #pragma unroll
        for (int kk = 0; kk < 4; ++kk)
            afrag2[kk] = *reinterpret_cast<const bf16x8*>(&xtile[row16][kgrp * 8 + kk * 32]);

        f32x4 acc2[8];
        #pragma unroll
        for (int t = 0; t < 8; ++t) acc2[t] = (f32x4){0.f, 0.f, 0.f, 0.f};
        #pragma unroll
        for (int t = 0; t < 8; ++t) {
            const float* wp = W2 + (size_t)(t * 16 + row16) * DIM + kgrp * 8;
            #pragma unroll
            for (int kk = 0; kk < 4; ++kk) {
                bf16x8 bfrag = ldw8(wp + kk * 32);
                acc2[t] = __builtin_amdgcn_mfma_f32_16x16x32_bf16(afrag2[kk], bfrag, acc2[t], 0, 0, 0);
            }
        }

        // result -> LDS vtile (2-way bank aliasing only; free per m136)
        #pragma unroll
        for (int r = 0; r < 4; ++r) {
            const int gm = kgrp * 4 + r;
            #pragma unroll
            for (int t = 0; t < 8; ++t)
                vtile[gm][t * 16 + row16] = acc2[t][r] + b2f8[t];
        }
    }
    __syncthreads();

    // ---- coalesced global vn_out store from vtile ----
    {
        const float* src = &vtile[gi][j * 8];
        float* dst = vn_out + (size_t)(G0 + gi) * DIM + j * 8;
        *reinterpret_cast<f32x4*>(dst)     = *reinterpret_cast<const f32x4*>(src);
        *reinterpret_cast<f32x4*>(dst + 4) = *reinterpret_cast<const f32x4*>(src + 4);
    }

    // ---- phase 3: h_out = h + vn_out[g], segment rows are cache-warm ----
    f32x4 w0 = *reinterpret_cast<const f32x4*>(&vtile[gi][j * 8]);
    f32x4 w1 = *reinterpret_cast<const f32x4*>(&vtile[gi][j * 8 + 4]);
    for (int n = s; n < e; ++n) {
        const float* p = h + (size_t)n * DIM + j * 8;
        f32x4 h0 = *reinterpret_cast<const f32x4*>(p);
        f32x4 h1 = *reinterpret_cast<const f32x4*>(p + 4);
        float* op = h_out + (size_t)n * DIM + j * 8;
        __builtin_nontemporal_store(h0 + w0, reinterpret_cast<f32x4*>(op));
        __builtin_nontemporal_store(h1 + w1, reinterpret_cast<f32x4*>(op + 4));
    }
}

// ---------------------------------------------------------------------------
extern "C" void kernel_launch(void* const* d_in, const int* in_sizes, int n_in,
                              void* d_out, int out_size, void* d_ws, size_t ws_size,
                              hipStream_t stream)
{
    const float* h    = (const float*)d_in[0];
    const int*   bat  = (const int*)d_in[1];
    const float* vn   = (const float*)d_in[2];
    const float* W1   = (const float*)d_in[3];
    const float* b1   = (const float*)d_in[4];
    const float* lng  = (const float*)d_in[5];
    const float* lnb  = (const float*)d_in[6];
    const float* W2   = (const float*)d_in[7];
    const float* b2v  = (const float*)d_in[8];

    const int n_nodes = in_sizes[0] / DIM;   // 500000
    const int nb      = in_sizes[2] / DIM;   // 8192

    float* out    = (float*)d_out;           // f32 output buffer
    float* h_out  = out;
    float* vn_out = out + (size_t)n_nodes * DIM;

    k_fused<<<nb / 16, 256, 0, stream>>>(h, bat, vn, W1, b1, lng, lnb,
                                         W2, b2v, vn_out, h_out, n_nodes);
}